// Round 6
// baseline (177.583 us; speedup 1.0000x reference)
//
#include <hip/hip_runtime.h>
#include <hip/hip_bf16.h>
#include <stdint.h>

// B=8, T=1024, D=U=640, H=10, d=64
#define B_DIM 8
#define T_DIM 1024
#define D_DIM 640
#define H_DIM 10
#define LOG2E 1.442695041f

typedef unsigned short ushort_t;
typedef __attribute__((ext_vector_type(8))) short short8;
typedef __attribute__((ext_vector_type(4))) float f32x4;

__device__ __forceinline__ ushort_t f32_to_bf16(float f) {
    unsigned int u = __builtin_bit_cast(unsigned int, f);
    u += 0x7fffu + ((u >> 16) & 1u);   // RNE
    return (ushort_t)(u >> 16);
}
__device__ __forceinline__ float v_exp2(float x) {
    float r; asm("v_exp_f32 %0, %1" : "=v"(r) : "v"(x)); return r;
}
__device__ __forceinline__ unsigned cvt_pk_bf16(float a, float b) {
    unsigned r; asm("v_cvt_pk_bf16_f32 %0, %1, %2" : "=v"(r) : "v"(a), "v"(b)); return r;
}

// async global->LDS (GEMM staging only). Dest = wave-uniform base + lane*16.
__device__ __forceinline__ void gload16(const void* g, void* l) {
    auto gp = reinterpret_cast<const __attribute__((address_space(1))) uint32_t*>(
        reinterpret_cast<uintptr_t>(g));
    auto lp = reinterpret_cast<__attribute__((address_space(3))) uint32_t*>(
        reinterpret_cast<uintptr_t>(l));
    __builtin_amdgcn_global_load_lds(gp, lp, 16, 0, 0);
}

// strip permutation: heavy strips (16/16/16/15 tiles) land in early blocks
__constant__ int SPERM[32] = {0,31,30,29,28,27,26,25,24,23,22,21,20,19,18,17,
                              16,15,14,13,12,11,10,9,8,7,6,5,4,3,2,1};

// ---------------------------------------------------------------------------
// Kernel A: fused { W transpose->bf16 (blocks 0..299) , x->bf16 (blocks 300+) }
// ---------------------------------------------------------------------------
__global__ __launch_bounds__(256) void convwt(
    const float* __restrict__ x,
    const float* __restrict__ Wq, const float* __restrict__ Wk, const float* __restrict__ Wv,
    ushort_t* __restrict__ xb, ushort_t* __restrict__ Wt)
{
    const int tid = threadIdx.x;
    if (blockIdx.x < 300) {
        const int w = blockIdx.x / 100, rem = blockIdx.x % 100;
        const int k0 = (rem % 10) * 64, n0 = (rem / 10) * 64;
        const float* W = (w == 0) ? Wq : (w == 1) ? Wk : Wv;
        ushort_t* Wo = Wt + (size_t)w * D_DIM * D_DIM;

        __shared__ alignas(16) ushort_t st[64][72];
        const int r = tid >> 2, cs = (tid & 3) * 16;
        #pragma unroll
        for (int j = 0; j < 4; ++j) {
            float4 v = *reinterpret_cast<const float4*>(
                &W[(size_t)(k0 + r) * D_DIM + n0 + cs + j * 4]);
            st[r][cs + j * 4 + 0] = f32_to_bf16(v.x);
            st[r][cs + j * 4 + 1] = f32_to_bf16(v.y);
            st[r][cs + j * 4 + 2] = f32_to_bf16(v.z);
            st[r][cs + j * 4 + 3] = f32_to_bf16(v.w);
        }
        __syncthreads();
        const int nr = tid >> 2, ks = (tid & 3) * 16;
        ushort_t tmp[16];
        #pragma unroll
        for (int j = 0; j < 16; ++j) tmp[j] = st[ks + j][nr];
        ushort_t* dst = &Wo[(size_t)(n0 + nr) * D_DIM + k0 + ks];
        *reinterpret_cast<short8*>(dst)     = *reinterpret_cast<const short8*>(&tmp[0]);
        *reinterpret_cast<short8*>(dst + 8) = *reinterpret_cast<const short8*>(&tmp[8]);
    } else {
        const int n8 = (B_DIM * T_DIM * D_DIM) / 8;
        for (int i = (blockIdx.x - 300) * 256 + tid; i < n8; i += 2048 * 256) {
            float4 a = *reinterpret_cast<const float4*>(&x[i * 8]);
            float4 b = *reinterpret_cast<const float4*>(&x[i * 8 + 4]);
            ushort_t o[8] = {f32_to_bf16(a.x), f32_to_bf16(a.y), f32_to_bf16(a.z), f32_to_bf16(a.w),
                             f32_to_bf16(b.x), f32_to_bf16(b.y), f32_to_bf16(b.z), f32_to_bf16(b.w)};
            *reinterpret_cast<short8*>(&xb[i * 8]) = *reinterpret_cast<const short8*>(o);
        }
    }
}

// ---------------------------------------------------------------------------
// Kernel B: bf16 MFMA GEMM (XCD-remapped flat grid of 960). Q,K row-major;
// V written per-head transposed Vt[((b*10+h)*64+d)*1024 + t].
// ---------------------------------------------------------------------------
__global__ __launch_bounds__(256) void gemm_qkv(
    const ushort_t* __restrict__ xb, const ushort_t* __restrict__ Wt,
    ushort_t* __restrict__ Qb, ushort_t* __restrict__ Kb, ushort_t* __restrict__ Vt)
{
    const int L = blockIdx.x;
    const int xcd = L & 7, j = L >> 3;
    const int m0 = (xcd * 8 + (j & 7)) * 128;
    const int nz = j >> 3;               // 0..14
    const int n0 = (nz % 5) * 128;
    const int w  = nz / 5;

    const ushort_t* Wm = Wt + (size_t)w * D_DIM * D_DIM;

    __shared__ alignas(16) ushort_t As[128 * 64];
    __shared__ alignas(16) ushort_t Bs[128 * 64];

    const int tid = threadIdx.x;
    const int lane = tid & 63, wave = tid >> 6;
    const int lo = lane & 15, g = lane >> 4;
    const int wm = wave >> 1, wn = wave & 1;
    const int srow = tid >> 3, schunk = tid & 7;

    f32x4 acc[4][4];
    #pragma unroll
    for (int i = 0; i < 4; ++i)
        #pragma unroll
        for (int jj = 0; jj < 4; ++jj) acc[i][jj] = (f32x4){0.f, 0.f, 0.f, 0.f};

    for (int k0 = 0; k0 < D_DIM; k0 += 64) {
        #pragma unroll
        for (int i = 0; i < 4; ++i) {
            int row = i * 32 + srow;
            int sc = schunk ^ (row & 7);
            gload16(&xb[(size_t)(m0 + row) * D_DIM + k0 + sc * 8], &As[i * 2048 + tid * 8]);
            gload16(&Wm[(size_t)(n0 + row) * D_DIM + k0 + sc * 8], &Bs[i * 2048 + tid * 8]);
        }
        __syncthreads();
        #pragma unroll
        for (int ks = 0; ks < 2; ++ks) {
            short8 af[4], bf[4];
            #pragma unroll
            for (int t = 0; t < 4; ++t) {
                int arow = wm * 64 + t * 16 + lo;
                int ach = (ks * 4 + g) ^ (arow & 7);
                af[t] = *reinterpret_cast<const short8*>(&As[arow * 64 + ach * 8]);
                int brow = wn * 64 + t * 16 + lo;
                int bch = (ks * 4 + g) ^ (brow & 7);
                bf[t] = *reinterpret_cast<const short8*>(&Bs[brow * 64 + bch * 8]);
            }
            __builtin_amdgcn_s_setprio(1);
            #pragma unroll
            for (int mi = 0; mi < 4; ++mi)
                #pragma unroll
                for (int ni = 0; ni < 4; ++ni)
                    acc[mi][ni] = __builtin_amdgcn_mfma_f32_16x16x32_bf16(
                        af[mi], bf[ni], acc[mi][ni], 0, 0, 0);
            __builtin_amdgcn_s_setprio(0);
        }
        __syncthreads();
    }

    if (w == 2) {
        #pragma unroll
        for (int mi = 0; mi < 4; ++mi)
            #pragma unroll
            for (int ni = 0; ni < 4; ++ni) {
                int row = m0 + wm * 64 + mi * 16 + g * 4;   // 4 consecutive tokens
                int col = n0 + wn * 64 + ni * 16 + lo;
                int bb = row >> 10, tt = row & 1023;
                int hh = col >> 6, dd = col & 63;
                ushort_t pk[4];
                #pragma unroll
                for (int r = 0; r < 4; ++r) pk[r] = f32_to_bf16(acc[mi][ni][r]);
                ushort4 o = make_ushort4(pk[0], pk[1], pk[2], pk[3]);
                *reinterpret_cast<ushort4*>(
                    &Vt[((size_t)(bb * H_DIM + hh) * 64 + dd) * T_DIM + tt]) = o;
            }
    } else {
        ushort_t* Y = (w == 0) ? Qb : Kb;
        #pragma unroll
        for (int mi = 0; mi < 4; ++mi)
            #pragma unroll
            for (int ni = 0; ni < 4; ++ni)
                #pragma unroll
                for (int r = 0; r < 4; ++r) {
                    int row = m0 + wm * 64 + mi * 16 + g * 4 + r;
                    int col = n0 + wn * 64 + ni * 16 + lo;
                    Y[(size_t)row * D_DIM + col] = f32_to_bf16(acc[mi][ni][r]);
                }
    }
}

// ---------------------------------------------------------------------------
// Kernel D: masks. qs = sign(sum|Q_h|)*mask (f32), km16 = sign(sum|K_h|) bf16.
// ---------------------------------------------------------------------------
__global__ __launch_bounds__(256) void masks_kernel(
    const ushort_t* __restrict__ Qb, const ushort_t* __restrict__ Kb,
    const int* __restrict__ msk, float* __restrict__ qs, ushort_t* __restrict__ km16)
{
    const int rowid = blockIdx.x * 32 + (threadIdx.x >> 3);   // h*8192 + b*1024 + t
    const int p = threadIdx.x & 7;
    const int h = rowid >> 13;
    const int rem = rowid & 8191;
    const ushort_t* qrow = &Qb[(size_t)rem * D_DIM + h * 64 + p * 8];
    const ushort_t* krow = &Kb[(size_t)rem * D_DIM + h * 64 + p * 8];
    unsigned int oq = 0, ok = 0;
    #pragma unroll
    for (int j = 0; j < 8; ++j) {
        oq |= (unsigned int)(qrow[j] & 0x7fff);
        ok |= (unsigned int)(krow[j] & 0x7fff);
    }
    #pragma unroll
    for (int m = 1; m < 8; m <<= 1) {
        oq |= (unsigned int)__shfl_xor((int)oq, m);
        ok |= (unsigned int)__shfl_xor((int)ok, m);
    }
    if (p == 0) {
        qs[rowid] = (oq != 0 ? 1.f : 0.f) * (float)msk[rem];
        km16[rowid] = (ok != 0) ? (ushort_t)0x3F80 : (ushort_t)0;
    }
}

// ---------------------------------------------------------------------------
// Kernel D2: per-row shift M: 16 if any unpadded key strictly before row,
// else -9984. One wave per (h,b); exclusive prefix-OR via ballot.
// ---------------------------------------------------------------------------
__global__ __launch_bounds__(64) void prefix_kernel(const ushort_t* __restrict__ km16,
                                                    float* __restrict__ Mv)
{
    const int hb = blockIdx.x;
    const int lane = threadIdx.x;
    const ushort_t* kr = &km16[(size_t)hb * T_DIM];
    float* mv = &Mv[(size_t)hb * T_DIM];
    bool running = false;
    for (int c = 0; c < 16; ++c) {
        ushort_t v = kr[c * 64 + lane];
        unsigned long long bal = __ballot(v != 0);
        unsigned long long pre = bal & ((1ull << lane) - 1ull);
        bool any = running || (pre != 0ull);
        mv[c * 64 + lane] = any ? 16.f : -9984.f;
        running = running || (bal != 0ull);
    }
}

// ---------------------------------------------------------------------------
// Kernel E: wave-independent flash attention. One WAVE = one (b,h, 32-row
// q-strip). Zero barriers, zero cross-wave coupling. K/V/Q fragments loaded
// directly global->VGPR (L2-resident per XCD after first touch). P goes
// through a wave-private 4KB LDS slice. Output written directly (no atomics).
// ---------------------------------------------------------------------------
__global__ __launch_bounds__(256, 3) void attn_wave(
    const ushort_t* __restrict__ Qb, const ushort_t* __restrict__ Kb,
    const ushort_t* __restrict__ Vt, const float* __restrict__ qs,
    const ushort_t* __restrict__ km16, const float* __restrict__ Mv,
    float* __restrict__ out)
{
    __shared__ alignas(16) ushort_t Pl[4][32 * 64];

    const int tid = threadIdx.x;
    const int lane = tid & 63, wave = tid >> 6;
    const int lo = lane & 15, g = lane >> 4;

    // mapping: same-(b,h) strips share an XCD; heavy strips in early blocks
    const int bi = blockIdx.x;                 // 0..639
    const int xcd = bi & 7, j = bi >> 3;       // j 0..79
    const int g8 = xcd + 8 * (j % 10);         // (b,h) group 0..79
    const int qg = j / 10;                     // 0..7
    const int s = SPERM[qg * 4 + wave];        // strip 0..31
    const int q0 = s * 32;
    const int b = g8 & 7, h = g8 >> 3;

    const size_t rowbase = (size_t)b * T_DIM;
    const int colbase = h * 64;
    const int hb = h * B_DIM + b;

    ushort_t* P = Pl[wave];

    // ---- Q fragments (A-operand): row = q0+ms*16+lo, k = ks*32+g*8+j ----
    short8 qf[2][2];
    #pragma unroll
    for (int ms = 0; ms < 2; ++ms)
        #pragma unroll
        for (int ks = 0; ks < 2; ++ks)
            qf[ms][ks] = *reinterpret_cast<const short8*>(
                &Qb[(rowbase + q0 + ms * 16 + lo) * D_DIM + colbase + ks * 32 + g * 8]);

    // ---- per-row exp2-domain constants ----
    float cAr[2][4], cBr[2][4];
    #pragma unroll
    for (int ms = 0; ms < 2; ++ms)
        #pragma unroll
        for (int r = 0; r < 4; ++r) {
            float M = Mv[(size_t)hb * T_DIM + q0 + ms * 16 + g * 4 + r];
            cAr[ms][r] = -M * LOG2E;                       // allowed
            cBr[ms][r] = cAr[ms][r] - 10000.0f * LOG2E;    // directional-masked
        }
    const float S2 = 0.125f * LOG2E;

    float lacc[2][4] = {{0.f}};
    f32x4 of[2][4];
    #pragma unroll
    for (int ms = 0; ms < 2; ++ms)
        #pragma unroll
        for (int df = 0; df < 4; ++df) of[ms][df] = (f32x4){0.f, 0.f, 0.f, 0.f};

    // tiles needed: strip 0 includes global row 0 (attends ALL keys)
    const int ktend = (s == 0) ? 16 : (((32 * s + 30) >> 6) + 1);

    for (int kt = 0; kt < ktend; ++kt) {
        const int k0 = kt * 64;

        // K fragments (B-operand): col = k0+nf*16+lo, k = ks*32+g*8+j
        const ushort_t* Kbase = &Kb[(rowbase + k0 + lo) * D_DIM + colbase + g * 8];
        short8 kf[4][2];
        #pragma unroll
        for (int nf = 0; nf < 4; ++nf)
            #pragma unroll
            for (int ks = 0; ks < 2; ++ks)
                kf[nf][ks] = *reinterpret_cast<const short8*>(
                    &Kbase[(size_t)(nf * 16) * D_DIM + ks * 32]);

        ushort_t kmu[4];
        #pragma unroll
        for (int nf = 0; nf < 4; ++nf)
            kmu[nf] = km16[(size_t)hb * T_DIM + k0 + nf * 16 + lo];

        // V^T fragments (B-operand for PV): col(d) = df*16+lo, k = ks*32+g*8+j
        // issue早 so HBM/L2 latency hides under QK + softmax
        const ushort_t* Vbase = &Vt[((size_t)(b * H_DIM + h) * 64 + lo) * T_DIM + k0 + g * 8];
        short8 vf[2][4];
        #pragma unroll
        for (int ks = 0; ks < 2; ++ks)
            #pragma unroll
            for (int df = 0; df < 4; ++df)
                vf[ks][df] = *reinterpret_cast<const short8*>(
                    &Vbase[(size_t)(df * 16) * T_DIM + ks * 32]);

        // S = Q K^T
        f32x4 sf[2][4];
        __builtin_amdgcn_s_setprio(1);
        #pragma unroll
        for (int ms = 0; ms < 2; ++ms)
            #pragma unroll
            for (int nf = 0; nf < 4; ++nf) {
                f32x4 z = (f32x4){0.f, 0.f, 0.f, 0.f};
                z = __builtin_amdgcn_mfma_f32_16x16x32_bf16(qf[ms][0], kf[nf][0], z, 0, 0, 0);
                z = __builtin_amdgcn_mfma_f32_16x16x32_bf16(qf[ms][1], kf[nf][1], z, 0, 0, 0);
                sf[ms][nf] = z;
            }
        __builtin_amdgcn_s_setprio(0);

        // fixed-shift softmax in exp2 domain; P (bf16) into wave-private LDS
        #pragma unroll
        for (int ms = 0; ms < 2; ++ms)
            #pragma unroll
            for (int r = 0; r < 4; ++r) {
                const int rowl = ms * 16 + g * 4 + r;      // 0..31 within strip
                const int trow = q0 + rowl;
                float p[4];
                #pragma unroll
                for (int nf = 0; nf < 4; ++nf) {
                    int kcol = k0 + nf * 16 + lo;
                    float cc = (kcol >= trow) ? cBr[ms][r] : cAr[ms][r];
                    cc = (kmu[nf] != 0) ? cc : -1e30f;     // key padding dominates
                    p[nf] = v_exp2(fmaf(sf[ms][nf][r], S2, cc));
                }
                lacc[ms][r] += (p[0] + p[1]) + (p[2] + p[3]);
                unsigned pk01 = cvt_pk_bf16(p[0], p[1]);
                unsigned pk23 = cvt_pk_bf16(p[2], p[3]);
                const int base = rowl * 64, sw = (rowl & 7);
                int c0 = lo,      h0 = ((c0 >> 3) ^ sw);
                int c1 = 16 + lo, h1 = ((c1 >> 3) ^ sw);
                int c2 = 32 + lo, h2 = ((c2 >> 3) ^ sw);
                int c3 = 48 + lo, h3 = ((c3 >> 3) ^ sw);
                P[base + h0 * 8 + (c0 & 7)] = (ushort_t)pk01;
                P[base + h1 * 8 + (c1 & 7)] = (ushort_t)(pk01 >> 16);
                P[base + h2 * 8 + (c2 & 7)] = (ushort_t)pk23;
                P[base + h3 * 8 + (c3 & 7)] = (ushort_t)(pk23 >> 16);
            }

        // O += P V  (wave-private LDS round trip; compiler inserts lgkmcnt)
        #pragma unroll
        for (int ks = 0; ks < 2; ++ks) {
            short8 pf[2];
            #pragma unroll
            for (int ms = 0; ms < 2; ++ms) {
                int row = ms * 16 + lo;
                int ch = (ks * 4 + g) ^ (row & 7);
                pf[ms] = *reinterpret_cast<const short8*>(&P[row * 64 + ch * 8]);
            }
            __builtin_amdgcn_s_setprio(1);
            #pragma unroll
            for (int ms = 0; ms < 2; ++ms)
                #pragma unroll
                for (int df = 0; df < 4; ++df)
                    of[ms][df] = __builtin_amdgcn_mfma_f32_16x16x32_bf16(
                        pf[ms], vf[ks][df], of[ms][df], 0, 0, 0);
            __builtin_amdgcn_s_setprio(0);
        }
    }

    // epilogue: reduce l across 16 lanes, scale by qs/l, store f32
    #pragma unroll
    for (int ms = 0; ms < 2; ++ms)
        #pragma unroll
        for (int r = 0; r < 4; ++r) {
            float l = lacc[ms][r];
            l += __shfl_xor(l, 1); l += __shfl_xor(l, 2);
            l += __shfl_xor(l, 4); l += __shfl_xor(l, 8);
            const int trow = q0 + ms * 16 + g * 4 + r;
            const float sc = qs[(size_t)hb * T_DIM + trow] / l;
            #pragma unroll
            for (int df = 0; df < 4; ++df)
                out[(rowbase + trow) * D_DIM + colbase + df * 16 + lo] = of[ms][df][r] * sc;
        }
}

// ---------------------------------------------------------------------------
extern "C" void kernel_launch(void* const* d_in, const int* in_sizes, int n_in,
                              void* d_out, int out_size, void* d_ws, size_t ws_size,
                              hipStream_t stream)
{
    const float* x   = (const float*)d_in[0];
    const int*   msk = (const int*)d_in[1];
    const float* Wq  = (const float*)d_in[2];
    const float* Wk  = (const float*)d_in[3];
    const float* Wv  = (const float*)d_in[4];
    float* out = (float*)d_out;

    // workspace layout (bytes)
    char* ws = (char*)d_ws;
    ushort_t* xb = (ushort_t*)(ws);                    // 10,485,760
    ushort_t* Wt = (ushort_t*)(ws + 10485760);         //  2,457,600
    ushort_t* Qb = (ushort_t*)(ws + 12943360);         // 10,485,760
    ushort_t* Kb = (ushort_t*)(ws + 23429120);         // 10,485,760
    ushort_t* Vt = (ushort_t*)(ws + 33914880);         // 10,485,760
    float*    qs = (float*)(ws + 44400640);            //    327,680
    ushort_t* km = (ushort_t*)(ws + 44728320);         //    163,840
    float*    Mv = (float*)(ws + 44892160);            //    327,680
    if (ws_size < 45219840) return;

    convwt<<<2348, 256, 0, stream>>>(x, Wq, Wk, Wv, xb, Wt);
    gemm_qkv<<<960, 256, 0, stream>>>(xb, Wt, Qb, Kb, Vt);
    masks_kernel<<<2560, 256, 0, stream>>>(Qb, Kb, msk, qs, km);
    prefix_kernel<<<80, 64, 0, stream>>>(km, Mv);
    attn_wave<<<640, 256, 0, stream>>>(Qb, Kb, Vt, qs, km, Mv, out);
}

// Round 7
// 79.757 us; speedup vs baseline: 2.2265x; 2.2265x over previous
//
#include <hip/hip_runtime.h>
#include <hip/hip_bf16.h>
#include <stdint.h>

// B=8, T=1024, D=U=640, H=10, d=64
#define B_DIM 8
#define T_DIM 1024
#define D_DIM 640
#define H_DIM 10
#define LOG2E 1.442695041f

typedef unsigned short ushort_t;
typedef __attribute__((ext_vector_type(8))) short short8;
typedef __attribute__((ext_vector_type(4))) float f32x4;
typedef __attribute__((ext_vector_type(16))) float f32x16;
typedef __attribute__((ext_vector_type(4))) unsigned int u32x4;

__device__ __forceinline__ ushort_t f32_to_bf16(float f) {
    unsigned int u = __builtin_bit_cast(unsigned int, f);
    u += 0x7fffu + ((u >> 16) & 1u);   // RNE
    return (ushort_t)(u >> 16);
}
__device__ __forceinline__ float v_exp2(float x) {
    float r; asm("v_exp_f32 %0, %1" : "=v"(r) : "v"(x)); return r;
}
__device__ __forceinline__ unsigned cvt_pk_bf16(float a, float b) {
    unsigned r; asm("v_cvt_pk_bf16_f32 %0, %1, %2" : "=v"(r) : "v"(a), "v"(b)); return r;
}
// async global->LDS (GEMM staging only)
__device__ __forceinline__ void gload16(const void* g, void* l) {
    auto gp = reinterpret_cast<const __attribute__((address_space(1))) uint32_t*>(
        reinterpret_cast<uintptr_t>(g));
    auto lp = reinterpret_cast<__attribute__((address_space(3))) uint32_t*>(
        reinterpret_cast<uintptr_t>(l));
    __builtin_amdgcn_global_load_lds(gp, lp, 16, 0, 0);
}

// strips sorted heavy-first by tile count: 0(16),31(16),30(16),29(15),...
__constant__ int SPERM[32] = {0,31,30,29,28,27,26,25,24,23,22,21,20,19,18,17,
                              16,15,14,13,12,11,10,9,8,7,6,5,4,3,2,1};

// ---------------------------------------------------------------------------
// Kernel A: fused { W transpose->bf16 (blocks 0..299) , x->bf16 (blocks 300+) }
// ---------------------------------------------------------------------------
__global__ __launch_bounds__(256) void convwt(
    const float* __restrict__ x,
    const float* __restrict__ Wq, const float* __restrict__ Wk, const float* __restrict__ Wv,
    ushort_t* __restrict__ xb, ushort_t* __restrict__ Wt)
{
    const int tid = threadIdx.x;
    if (blockIdx.x < 300) {
        const int w = blockIdx.x / 100, rem = blockIdx.x % 100;
        const int k0 = (rem % 10) * 64, n0 = (rem / 10) * 64;
        const float* W = (w == 0) ? Wq : (w == 1) ? Wk : Wv;
        ushort_t* Wo = Wt + (size_t)w * D_DIM * D_DIM;

        __shared__ alignas(16) ushort_t st[64][72];
        const int r = tid >> 2, cs = (tid & 3) * 16;
        #pragma unroll
        for (int j = 0; j < 4; ++j) {
            float4 v = *reinterpret_cast<const float4*>(
                &W[(size_t)(k0 + r) * D_DIM + n0 + cs + j * 4]);
            st[r][cs + j * 4 + 0] = f32_to_bf16(v.x);
            st[r][cs + j * 4 + 1] = f32_to_bf16(v.y);
            st[r][cs + j * 4 + 2] = f32_to_bf16(v.z);
            st[r][cs + j * 4 + 3] = f32_to_bf16(v.w);
        }
        __syncthreads();
        const int nr = tid >> 2, ks = (tid & 3) * 16;
        ushort_t tmp[16];
        #pragma unroll
        for (int j = 0; j < 16; ++j) tmp[j] = st[ks + j][nr];
        ushort_t* dst = &Wo[(size_t)(n0 + nr) * D_DIM + k0 + ks];
        *reinterpret_cast<short8*>(dst)     = *reinterpret_cast<const short8*>(&tmp[0]);
        *reinterpret_cast<short8*>(dst + 8) = *reinterpret_cast<const short8*>(&tmp[8]);
    } else {
        const int n8 = (B_DIM * T_DIM * D_DIM) / 8;
        for (int i = (blockIdx.x - 300) * 256 + tid; i < n8; i += 2048 * 256) {
            float4 a = *reinterpret_cast<const float4*>(&x[i * 8]);
            float4 b = *reinterpret_cast<const float4*>(&x[i * 8 + 4]);
            ushort_t o[8] = {f32_to_bf16(a.x), f32_to_bf16(a.y), f32_to_bf16(a.z), f32_to_bf16(a.w),
                             f32_to_bf16(b.x), f32_to_bf16(b.y), f32_to_bf16(b.z), f32_to_bf16(b.w)};
            *reinterpret_cast<short8*>(&xb[i * 8]) = *reinterpret_cast<const short8*>(o);
        }
    }
}

// ---------------------------------------------------------------------------
// Kernel B: bf16 MFMA GEMM. Outputs written in 32x32x16-MFMA FRAGMENT layouts:
//  QF: (((hb*32+s)*4+kc)*64 + lane)*8+jj  = Q[32s+(l&31)][64h+16kc+8(l>>5)+jj]
//  KF: ((((hb*16+kt)*2+f)*4+kc)*64+lane)*8+jj = K[64kt+32f+(l&31)][...d...]
//  VF: ((((hb*16+kt)*4+c)*2+df)*64+lane)*8+jj = V[64kt+16c+8(l>>5)+jj][64h+32df+(l&31)]
// Also computes qs = sign(sum|Q_h|)*mask and km16 = sign(sum|K_h|) in-epilogue.
// ---------------------------------------------------------------------------
__global__ __launch_bounds__(256) void gemm_qkv(
    const ushort_t* __restrict__ xb, const ushort_t* __restrict__ Wt,
    const int* __restrict__ msk,
    ushort_t* __restrict__ QF, ushort_t* __restrict__ KF, ushort_t* __restrict__ VF,
    float* __restrict__ qs, ushort_t* __restrict__ km16)
{
    const int L = blockIdx.x;
    const int xcd = L & 7, j = L >> 3;
    const int m0 = (xcd * 8 + (j & 7)) * 128;
    const int nz = j >> 3;               // 0..14
    const int n0 = (nz % 5) * 128;
    const int w  = nz / 5;

    const ushort_t* Wm = Wt + (size_t)w * D_DIM * D_DIM;

    __shared__ alignas(16) ushort_t As[128 * 64];
    __shared__ alignas(16) ushort_t Bs[128 * 64];

    const int tid = threadIdx.x;
    const int lane = tid & 63, wave = tid >> 6;
    const int lo = lane & 15, g = lane >> 4;
    const int wm = wave >> 1, wn = wave & 1;
    const int srow = tid >> 3, schunk = tid & 7;

    f32x4 acc[4][4];
    #pragma unroll
    for (int i = 0; i < 4; ++i)
        #pragma unroll
        for (int jj = 0; jj < 4; ++jj) acc[i][jj] = (f32x4){0.f, 0.f, 0.f, 0.f};

    for (int k0 = 0; k0 < D_DIM; k0 += 64) {
        #pragma unroll
        for (int i = 0; i < 4; ++i) {
            int row = i * 32 + srow;
            int sc = schunk ^ (row & 7);
            gload16(&xb[(size_t)(m0 + row) * D_DIM + k0 + sc * 8], &As[i * 2048 + tid * 8]);
            gload16(&Wm[(size_t)(n0 + row) * D_DIM + k0 + sc * 8], &Bs[i * 2048 + tid * 8]);
        }
        __syncthreads();
        #pragma unroll
        for (int ks = 0; ks < 2; ++ks) {
            short8 af[4], bf[4];
            #pragma unroll
            for (int t = 0; t < 4; ++t) {
                int arow = wm * 64 + t * 16 + lo;
                int ach = (ks * 4 + g) ^ (arow & 7);
                af[t] = *reinterpret_cast<const short8*>(&As[arow * 64 + ach * 8]);
                int brow = wn * 64 + t * 16 + lo;
                int bch = (ks * 4 + g) ^ (brow & 7);
                bf[t] = *reinterpret_cast<const short8*>(&Bs[brow * 64 + bch * 8]);
            }
            __builtin_amdgcn_s_setprio(1);
            #pragma unroll
            for (int mi = 0; mi < 4; ++mi)
                #pragma unroll
                for (int ni = 0; ni < 4; ++ni)
                    acc[mi][ni] = __builtin_amdgcn_mfma_f32_16x16x32_bf16(
                        af[mi], bf[ni], acc[mi][ni], 0, 0, 0);
            __builtin_amdgcn_s_setprio(0);
        }
        __syncthreads();
    }

    const int hh = (n0 >> 6) + wn;           // head 0..9 for this wave's half
    const int bb = m0 >> 10;                 // batch
    const int hb = hh * 8 + bb;
    const int ktw = ((m0 & 1023) >> 6) + wm; // 64-row tile index

    if (w == 2) {
        // V -> VF fragment layout; 4 consecutive keys pack into ushort4
        const int hiv = g >> 1, jj0 = (g & 1) * 4;
        #pragma unroll
        for (int mi = 0; mi < 4; ++mi)
            #pragma unroll
            for (int ni = 0; ni < 4; ++ni) {
                const int df = ni >> 1, l31v = (ni & 1) * 16 + lo;
                size_t idx = ((((size_t)(hb * 16 + ktw) * 4 + mi) * 2 + df) * 64
                              + hiv * 32 + l31v) * 8 + jj0;
                ushort4 o = make_ushort4(f32_to_bf16(acc[mi][ni][0]), f32_to_bf16(acc[mi][ni][1]),
                                         f32_to_bf16(acc[mi][ni][2]), f32_to_bf16(acc[mi][ni][3]));
                *reinterpret_cast<ushort4*>(&VF[idx]) = o;
            }
    } else {
        // sign masks (reduce |acc| over the head's 64 cols: 4 ni x 16 lanes)
        #pragma unroll
        for (int mi = 0; mi < 4; ++mi)
            #pragma unroll
            for (int r = 0; r < 4; ++r) {
                float s_ = fabsf(acc[mi][0][r]) + fabsf(acc[mi][1][r])
                         + fabsf(acc[mi][2][r]) + fabsf(acc[mi][3][r]);
                #pragma unroll
                for (int m = 1; m < 16; m <<= 1) s_ += __shfl_xor(s_, m);
                if (lo == 0) {
                    int row = m0 + wm * 64 + mi * 16 + g * 4 + r;
                    int rowid = hh * 8192 + row;
                    if (w == 0) qs[rowid] = (s_ > 0.f ? 1.f : 0.f) * (float)msk[row];
                    else        km16[rowid] = (s_ > 0.f) ? (ushort_t)0x3F80 : (ushort_t)0;
                }
            }
        // fragment-layout stores
        const int hi2 = lo >> 3, jjq = lo & 7;
        const int s32base = ((m0 & 1023) + wm * 64) >> 5;
        #pragma unroll
        for (int mi = 0; mi < 4; ++mi)
            #pragma unroll
            for (int ni = 0; ni < 4; ++ni)
                #pragma unroll
                for (int r = 0; r < 4; ++r) {
                    int l31 = (mi & 1) * 16 + g * 4 + r;
                    if (w == 0) {
                        int s32 = s32base + (mi >> 1);
                        size_t idx = (((size_t)(hb * 32 + s32) * 4 + ni) * 64
                                      + hi2 * 32 + l31) * 8 + jjq;
                        QF[idx] = f32_to_bf16(acc[mi][ni][r]);
                    } else {
                        int f = (mi >> 1) & 1;
                        size_t idx = ((((size_t)(hb * 16 + ktw) * 2 + f) * 4 + ni) * 64
                                      + hi2 * 32 + l31) * 8 + jjq;
                        KF[idx] = f32_to_bf16(acc[mi][ni][r]);
                    }
                }
    }
}

// ---------------------------------------------------------------------------
// Kernel C: wave-independent flash attention, 32x32x16 MFMA, swapped QK^T.
// One WAVE = one (b,h, 32-row q-strip). Zero barriers. All operand loads are
// coalesced dwordx4 from fragment-layout buffers. P stays in registers:
// cvt_pk_bf16 + v_permlane32_swap converts S^T C-layout -> PV A-fragments.
// ---------------------------------------------------------------------------
__global__ __launch_bounds__(256, 3) void attn_wave(
    const ushort_t* __restrict__ QF, const ushort_t* __restrict__ KF,
    const ushort_t* __restrict__ VF, const float* __restrict__ qs,
    const ushort_t* __restrict__ km16, float* __restrict__ out)
{
    __shared__ float scs[4][32];
    const int tid = threadIdx.x, lane = tid & 63, wave = tid >> 6;
    const int l31 = lane & 31, hi = lane >> 5;

    const int bid = blockIdx.x, xcd = bid & 7, j = bid >> 3;
    const int g8 = xcd + 8 * (j % 10), qg = j / 10;
    const int s = SPERM[qg * 4 + wave], q0 = s * 32;
    const int b = g8 & 7, h = g8 >> 3, hb = h * 8 + b;

    // --- probe permlane32_swap direction (HW variant), wave-uniform ---
    unsigned pva = (unsigned)lane, pvb = 64u + (unsigned)lane;
    asm volatile("v_permlane32_swap_b32 %0, %1" : "+v"(pva), "+v"(pvb));
    const bool v1 = (__builtin_amdgcn_readfirstlane((int)pva) >= 96);

    const ushort_t* QFh = QF + (size_t)(hb * 32 + s) * 2048;
    const ushort_t* KFh = KF + (size_t)hb * 16 * 4096;
    const ushort_t* VFh = VF + (size_t)hb * 16 * 4096;
    const ushort_t* kmr = km16 + (size_t)hb * 1024;

    // Q fragments (B-operand), loop-invariant
    short8 qf[4];
    #pragma unroll
    for (int kc = 0; kc < 4; ++kc)
        qf[kc] = *reinterpret_cast<const short8*>(&QFh[kc * 512 + lane * 8]);

    // per-row shift M: any unpadded key strictly before row q0+l31?
    bool anyPrior = false;
    for (int c = 0; c < (q0 >> 6); ++c) {
        ushort_t v = kmr[c * 64 + lane];
        anyPrior = anyPrior || (__ballot(v != 0) != 0ull);
    }
    float M;
    {
        ushort_t v = kmr[(q0 & ~63) + lane];
        unsigned long long bal = __ballot(v != 0);
        unsigned long long pre = bal & ((1ull << ((q0 & 63) + l31)) - 1ull);
        M = (anyPrior || pre != 0ull) ? 16.f : -9984.f;
    }
    const float cA = -M * LOG2E;
    const float cB = cA - 10000.0f * LOG2E;
    const float S2 = 0.125f * LOG2E;
    const int trow = q0 + l31;

    float lacc = 0.f;
    f32x16 of0, of1;
    #pragma unroll
    for (int i = 0; i < 16; ++i) { of0[i] = 0.f; of1[i] = 0.f; }

    const int ktend = (s == 0) ? 16 : ((s >> 1) + 1);

    for (int kt = 0; kt < ktend; ++kt) {
        const int k0 = kt * 64;
        const ushort_t* KT = &KFh[kt * 4096];
        const ushort_t* VT = &VFh[kt * 4096];

        // K fragments (A-operand): 8 coalesced dwordx4
        short8 kf[2][4];
        #pragma unroll
        for (int f = 0; f < 2; ++f)
            #pragma unroll
            for (int kc = 0; kc < 4; ++kc)
                kf[f][kc] = *reinterpret_cast<const short8*>(&KT[(f * 4 + kc) * 512 + lane * 8]);
        // V fragments c=0,1 issued early
        short8 vfA[2][2];
        #pragma unroll
        for (int c = 0; c < 2; ++c)
            #pragma unroll
            for (int df = 0; df < 2; ++df)
                vfA[c][df] = *reinterpret_cast<const short8*>(&VT[(c * 2 + df) * 512 + lane * 8]);
        // key masks: 4 keys per (f,rr) group
        ushort4 kq[2][4];
        #pragma unroll
        for (int f = 0; f < 2; ++f)
            #pragma unroll
            for (int rr = 0; rr < 4; ++rr)
                kq[f][rr] = *reinterpret_cast<const ushort4*>(&kmr[k0 + f * 32 + rr * 8 + hi * 4]);

        unsigned pk[2][8];
        short8 vfB[2][2];
        #pragma unroll
        for (int f = 0; f < 2; ++f) {
            // S^T = K Q^T over d=64 (4 chained K=16 mfmas)
            f32x16 sf;
            #pragma unroll
            for (int i = 0; i < 16; ++i) sf[i] = 0.f;
            __builtin_amdgcn_s_setprio(1);
            #pragma unroll
            for (int kc = 0; kc < 4; ++kc)
                sf = __builtin_amdgcn_mfma_f32_32x32x16_bf16(kf[f][kc], qf[kc], sf, 0, 0, 0);
            __builtin_amdgcn_s_setprio(0);
            if (f == 0) {   // issue V c=2,3 loads under softmax
                #pragma unroll
                for (int c = 0; c < 2; ++c)
                    #pragma unroll
                    for (int df = 0; df < 2; ++df)
                        vfB[c][df] = *reinterpret_cast<const short8*>(
                            &VT[((c + 2) * 2 + df) * 512 + lane * 8]);
            }
            // fixed-shift softmax in exp2 domain; immediate bf16 pack
            #pragma unroll
            for (int rr = 0; rr < 4; ++rr) {
                const int kbase = k0 + f * 32 + rr * 8 + hi * 4;
                const ushort_t* kmv = reinterpret_cast<const ushort_t*>(&kq[f][rr]);
                float p[4];
                #pragma unroll
                for (int ri = 0; ri < 4; ++ri) {
                    float cc = (kbase + ri >= trow) ? cB : cA;
                    cc = kmv[ri] ? cc : -1e30f;
                    p[ri] = v_exp2(fmaf(sf[rr * 4 + ri], S2, cc));
                    lacc += p[ri];
                }
                pk[f][rr * 2 + 0] = cvt_pk_bf16(p[0], p[1]);
                pk[f][rr * 2 + 1] = cvt_pk_bf16(p[2], p[3]);
            }
        }

        // PV: assemble A-fragments via permlane32_swap, accumulate O
        #pragma unroll
        for (int c = 0; c < 4; ++c) {
            const int f = c >> 1, o = (c & 1) * 4;
            unsigned a0 = pk[f][o + 0], b0 = pk[f][o + 2];
            unsigned a1 = pk[f][o + 1], b1 = pk[f][o + 3];
            if (v1) {
                asm volatile("v_permlane32_swap_b32 %0, %1" : "+v"(b0), "+v"(a0));
                asm volatile("v_permlane32_swap_b32 %0, %1" : "+v"(b1), "+v"(a1));
            } else {
                asm volatile("v_permlane32_swap_b32 %0, %1" : "+v"(a0), "+v"(b0));
                asm volatile("v_permlane32_swap_b32 %0, %1" : "+v"(a1), "+v"(b1));
            }
            u32x4 pau = {a0, a1, b0, b1};
            short8 pa = __builtin_bit_cast(short8, pau);
            short8 v0 = (c < 2) ? vfA[c][0] : vfB[c - 2][0];
            short8 v1f = (c < 2) ? vfA[c][1] : vfB[c - 2][1];
            __builtin_amdgcn_s_setprio(1);
            of0 = __builtin_amdgcn_mfma_f32_32x32x16_bf16(pa, v0, of0, 0, 0, 0);
            of1 = __builtin_amdgcn_mfma_f32_32x32x16_bf16(pa, v1f, of1, 0, 0, 0);
            __builtin_amdgcn_s_setprio(0);
        }
    }

    // epilogue: row scale qs/l distributed via tiny per-wave LDS slice
    float ltot = lacc + __shfl_xor(lacc, 32);
    if (hi == 0)
        scs[wave][l31] = qs[(size_t)hb * 1024 + q0 + l31] / ltot;
    const size_t obase = ((size_t)b * T_DIM + q0) * D_DIM + h * 64;
    #pragma unroll
    for (int reg = 0; reg < 16; ++reg) {
        const int qrow = (reg & 3) + 8 * (reg >> 2) + 4 * hi;
        const float sc = scs[wave][qrow];
        out[obase + (size_t)qrow * D_DIM + l31]      = of0[reg] * sc;
        out[obase + (size_t)qrow * D_DIM + 32 + l31] = of1[reg] * sc;
    }
}

// ---------------------------------------------------------------------------
extern "C" void kernel_launch(void* const* d_in, const int* in_sizes, int n_in,
                              void* d_out, int out_size, void* d_ws, size_t ws_size,
                              hipStream_t stream)
{
    const float* x   = (const float*)d_in[0];
    const int*   msk = (const int*)d_in[1];
    const float* Wq  = (const float*)d_in[2];
    const float* Wk  = (const float*)d_in[3];
    const float* Wv  = (const float*)d_in[4];
    float* out = (float*)d_out;

    // workspace layout (bytes)
    char* ws = (char*)d_ws;
    ushort_t* xb = (ushort_t*)(ws);                    // 10,485,760
    ushort_t* Wt = (ushort_t*)(ws + 10485760);         //  2,457,600
    ushort_t* QF = (ushort_t*)(ws + 12943360);         // 10,485,760
    ushort_t* KF = (ushort_t*)(ws + 23429120);         // 10,485,760
    ushort_t* VF = (ushort_t*)(ws + 33914880);         // 10,485,760
    float*    qs = (float*)(ws + 44400640);            //    327,680
    ushort_t* km = (ushort_t*)(ws + 44728320);         //    163,840
    if (ws_size < 44892160) return;

    convwt<<<2348, 256, 0, stream>>>(x, Wq, Wk, Wv, xb, Wt);
    gemm_qkv<<<960, 256, 0, stream>>>(xb, Wt, msk, QF, KF, VF, qs, km);
    attn_wave<<<640, 256, 0, stream>>>(QF, KF, VF, qs, km, out);
}

// Round 8
// 79.653 us; speedup vs baseline: 2.2295x; 1.0013x over previous
//
#include <hip/hip_runtime.h>
#include <hip/hip_bf16.h>
#include <stdint.h>

// B=8, T=1024, D=U=640, H=10, d=64
#define B_DIM 8
#define T_DIM 1024
#define D_DIM 640
#define H_DIM 10
#define LOG2E 1.442695041f

typedef unsigned short ushort_t;
typedef __attribute__((ext_vector_type(8))) short short8;
typedef __attribute__((ext_vector_type(4))) float f32x4;
typedef __attribute__((ext_vector_type(16))) float f32x16;
typedef __attribute__((ext_vector_type(4))) unsigned int u32x4;

__device__ __forceinline__ ushort_t f32_to_bf16(float f) {
    unsigned int u = __builtin_bit_cast(unsigned int, f);
    u += 0x7fffu + ((u >> 16) & 1u);   // RNE
    return (ushort_t)(u >> 16);
}
__device__ __forceinline__ float v_exp2(float x) {
    float r; asm("v_exp_f32 %0, %1" : "=v"(r) : "v"(x)); return r;
}
__device__ __forceinline__ unsigned cvt_pk_bf16(float a, float b) {
    unsigned r; asm("v_cvt_pk_bf16_f32 %0, %1, %2" : "=v"(r) : "v"(a), "v"(b)); return r;
}
// async global->LDS (GEMM staging only)
__device__ __forceinline__ void gload16(const void* g, void* l) {
    auto gp = reinterpret_cast<const __attribute__((address_space(1))) uint32_t*>(
        reinterpret_cast<uintptr_t>(g));
    auto lp = reinterpret_cast<__attribute__((address_space(3))) uint32_t*>(
        reinterpret_cast<uintptr_t>(l));
    __builtin_amdgcn_global_load_lds(gp, lp, 16, 0, 0);
}

// strips sorted heavy-first by tile count: 0(16),31(16),30(16),29(15),...
__constant__ int SPERM[32] = {0,31,30,29,28,27,26,25,24,23,22,21,20,19,18,17,
                              16,15,14,13,12,11,10,9,8,7,6,5,4,3,2,1};

// ---------------------------------------------------------------------------
// Kernel A: fused { W transpose->bf16 (blocks 0..299) , x->bf16 (blocks 300+) }
// ---------------------------------------------------------------------------
__global__ __launch_bounds__(256) void convwt(
    const float* __restrict__ x,
    const float* __restrict__ Wq, const float* __restrict__ Wk, const float* __restrict__ Wv,
    ushort_t* __restrict__ xb, ushort_t* __restrict__ Wt)
{
    const int tid = threadIdx.x;
    if (blockIdx.x < 300) {
        const int w = blockIdx.x / 100, rem = blockIdx.x % 100;
        const int k0 = (rem % 10) * 64, n0 = (rem / 10) * 64;
        const float* W = (w == 0) ? Wq : (w == 1) ? Wk : Wv;
        ushort_t* Wo = Wt + (size_t)w * D_DIM * D_DIM;

        __shared__ alignas(16) ushort_t st[64][72];
        const int r = tid >> 2, cs = (tid & 3) * 16;
        #pragma unroll
        for (int j = 0; j < 4; ++j) {
            float4 v = *reinterpret_cast<const float4*>(
                &W[(size_t)(k0 + r) * D_DIM + n0 + cs + j * 4]);
            st[r][cs + j * 4 + 0] = f32_to_bf16(v.x);
            st[r][cs + j * 4 + 1] = f32_to_bf16(v.y);
            st[r][cs + j * 4 + 2] = f32_to_bf16(v.z);
            st[r][cs + j * 4 + 3] = f32_to_bf16(v.w);
        }
        __syncthreads();
        const int nr = tid >> 2, ks = (tid & 3) * 16;
        ushort_t tmp[16];
        #pragma unroll
        for (int j = 0; j < 16; ++j) tmp[j] = st[ks + j][nr];
        ushort_t* dst = &Wo[(size_t)(n0 + nr) * D_DIM + k0 + ks];
        *reinterpret_cast<short8*>(dst)     = *reinterpret_cast<const short8*>(&tmp[0]);
        *reinterpret_cast<short8*>(dst + 8) = *reinterpret_cast<const short8*>(&tmp[8]);
    } else {
        const int n8 = (B_DIM * T_DIM * D_DIM) / 8;
        for (int i = (blockIdx.x - 300) * 256 + tid; i < n8; i += 2048 * 256) {
            float4 a = *reinterpret_cast<const float4*>(&x[i * 8]);
            float4 b = *reinterpret_cast<const float4*>(&x[i * 8 + 4]);
            ushort_t o[8] = {f32_to_bf16(a.x), f32_to_bf16(a.y), f32_to_bf16(a.z), f32_to_bf16(a.w),
                             f32_to_bf16(b.x), f32_to_bf16(b.y), f32_to_bf16(b.z), f32_to_bf16(b.w)};
            *reinterpret_cast<short8*>(&xb[i * 8]) = *reinterpret_cast<const short8*>(o);
        }
    }
}

// ---------------------------------------------------------------------------
// Kernel B: bf16 MFMA GEMM. Outputs written in 32x32x16-MFMA FRAGMENT layouts:
//  QF: (((hb*32+s)*4+kc)*64 + lane)*8+jj  = Q[32s+(l&31)][64h+16kc+8(l>>5)+jj]
//  KF: ((((hb*16+kt)*2+f)*4+kc)*64+lane)*8+jj = K[64kt+32f+(l&31)][...d...]
//  VF: ((((hb*16+kt)*4+c)*2+df)*64+lane)*8+jj = V[64kt+16c+8(l>>5)+jj][64h+32df+(l&31)]
// Also computes qs = sign(sum|Q_h|)*mask and km16 = sign(sum|K_h|) in-epilogue.
// ---------------------------------------------------------------------------
__global__ __launch_bounds__(256) void gemm_qkv(
    const ushort_t* __restrict__ xb, const ushort_t* __restrict__ Wt,
    const int* __restrict__ msk,
    ushort_t* __restrict__ QF, ushort_t* __restrict__ KF, ushort_t* __restrict__ VF,
    float* __restrict__ qs, ushort_t* __restrict__ km16)
{
    const int L = blockIdx.x;
    const int xcd = L & 7, j = L >> 3;
    const int m0 = (xcd * 8 + (j & 7)) * 128;
    const int nz = j >> 3;               // 0..14
    const int n0 = (nz % 5) * 128;
    const int w  = nz / 5;

    const ushort_t* Wm = Wt + (size_t)w * D_DIM * D_DIM;

    __shared__ alignas(16) ushort_t As[128 * 64];
    __shared__ alignas(16) ushort_t Bs[128 * 64];

    const int tid = threadIdx.x;
    const int lane = tid & 63, wave = tid >> 6;
    const int lo = lane & 15, g = lane >> 4;
    const int wm = wave >> 1, wn = wave & 1;
    const int srow = tid >> 3, schunk = tid & 7;

    f32x4 acc[4][4];
    #pragma unroll
    for (int i = 0; i < 4; ++i)
        #pragma unroll
        for (int jj = 0; jj < 4; ++jj) acc[i][jj] = (f32x4){0.f, 0.f, 0.f, 0.f};

    for (int k0 = 0; k0 < D_DIM; k0 += 64) {
        #pragma unroll
        for (int i = 0; i < 4; ++i) {
            int row = i * 32 + srow;
            int sc = schunk ^ (row & 7);
            gload16(&xb[(size_t)(m0 + row) * D_DIM + k0 + sc * 8], &As[i * 2048 + tid * 8]);
            gload16(&Wm[(size_t)(n0 + row) * D_DIM + k0 + sc * 8], &Bs[i * 2048 + tid * 8]);
        }
        __syncthreads();
        #pragma unroll
        for (int ks = 0; ks < 2; ++ks) {
            short8 af[4], bf[4];
            #pragma unroll
            for (int t = 0; t < 4; ++t) {
                int arow = wm * 64 + t * 16 + lo;
                int ach = (ks * 4 + g) ^ (arow & 7);
                af[t] = *reinterpret_cast<const short8*>(&As[arow * 64 + ach * 8]);
                int brow = wn * 64 + t * 16 + lo;
                int bch = (ks * 4 + g) ^ (brow & 7);
                bf[t] = *reinterpret_cast<const short8*>(&Bs[brow * 64 + bch * 8]);
            }
            __builtin_amdgcn_s_setprio(1);
            #pragma unroll
            for (int mi = 0; mi < 4; ++mi)
                #pragma unroll
                for (int ni = 0; ni < 4; ++ni)
                    acc[mi][ni] = __builtin_amdgcn_mfma_f32_16x16x32_bf16(
                        af[mi], bf[ni], acc[mi][ni], 0, 0, 0);
            __builtin_amdgcn_s_setprio(0);
        }
        __syncthreads();
    }

    const int hh = (n0 >> 6) + wn;           // head 0..9 for this wave's half
    const int bb = m0 >> 10;                 // batch
    const int hb = hh * 8 + bb;
    const int ktw = ((m0 & 1023) >> 6) + wm; // 64-row tile index

    if (w == 2) {
        // V -> VF fragment layout; 4 consecutive keys pack into ushort4
        const int hiv = g >> 1, jj0 = (g & 1) * 4;
        #pragma unroll
        for (int mi = 0; mi < 4; ++mi)
            #pragma unroll
            for (int ni = 0; ni < 4; ++ni) {
                const int df = ni >> 1, l31v = (ni & 1) * 16 + lo;
                size_t idx = ((((size_t)(hb * 16 + ktw) * 4 + mi) * 2 + df) * 64
                              + hiv * 32 + l31v) * 8 + jj0;
                ushort4 o = make_ushort4(f32_to_bf16(acc[mi][ni][0]), f32_to_bf16(acc[mi][ni][1]),
                                         f32_to_bf16(acc[mi][ni][2]), f32_to_bf16(acc[mi][ni][3]));
                *reinterpret_cast<ushort4*>(&VF[idx]) = o;
            }
    } else {
        // sign masks (reduce |acc| over the head's 64 cols: 4 ni x 16 lanes)
        #pragma unroll
        for (int mi = 0; mi < 4; ++mi)
            #pragma unroll
            for (int r = 0; r < 4; ++r) {
                float s_ = fabsf(acc[mi][0][r]) + fabsf(acc[mi][1][r])
                         + fabsf(acc[mi][2][r]) + fabsf(acc[mi][3][r]);
                #pragma unroll
                for (int m = 1; m < 16; m <<= 1) s_ += __shfl_xor(s_, m);
                if (lo == 0) {
                    int row = m0 + wm * 64 + mi * 16 + g * 4 + r;
                    int rowid = hh * 8192 + row;
                    if (w == 0) qs[rowid] = (s_ > 0.f ? 1.f : 0.f) * (float)msk[row];
                    else        km16[rowid] = (s_ > 0.f) ? (ushort_t)0x3F80 : (ushort_t)0;
                }
            }
        // fragment-layout stores
        const int hi2 = lo >> 3, jjq = lo & 7;
        const int s32base = ((m0 & 1023) + wm * 64) >> 5;
        #pragma unroll
        for (int mi = 0; mi < 4; ++mi)
            #pragma unroll
            for (int ni = 0; ni < 4; ++ni)
                #pragma unroll
                for (int r = 0; r < 4; ++r) {
                    int l31 = (mi & 1) * 16 + g * 4 + r;
                    if (w == 0) {
                        int s32 = s32base + (mi >> 1);
                        size_t idx = (((size_t)(hb * 32 + s32) * 4 + ni) * 64
                                      + hi2 * 32 + l31) * 8 + jjq;
                        QF[idx] = f32_to_bf16(acc[mi][ni][r]);
                    } else {
                        int f = (mi >> 1) & 1;
                        size_t idx = ((((size_t)(hb * 16 + ktw) * 2 + f) * 4 + ni) * 64
                                      + hi2 * 32 + l31) * 8 + jjq;
                        KF[idx] = f32_to_bf16(acc[mi][ni][r]);
                    }
                }
    }
}

// ---------------------------------------------------------------------------
// Kernel C: wave-independent flash attention, 32x32x16 MFMA, swapped QK^T.
// One WAVE = one (b,h, 32-row q-strip). Zero barriers. All operand loads are
// coalesced dwordx4 from fragment-layout buffers. P stays in registers:
// cvt_pk_bf16 + v_permlane32_swap converts S^T C-layout -> PV A-fragments.
// ---------------------------------------------------------------------------
__global__ __launch_bounds__(256, 3) void attn_wave(
    const ushort_t* __restrict__ QF, const ushort_t* __restrict__ KF,
    const ushort_t* __restrict__ VF, const float* __restrict__ qs,
    const ushort_t* __restrict__ km16, float* __restrict__ out)
{
    __shared__ float scs[4][32];
    const int tid = threadIdx.x, lane = tid & 63, wave = tid >> 6;
    const int l31 = lane & 31, hi = lane >> 5;

    const int bid = blockIdx.x, xcd = bid & 7, j = bid >> 3;
    const int g8 = xcd + 8 * (j % 10), qg = j / 10;
    const int s = SPERM[qg * 4 + wave], q0 = s * 32;
    const int b = g8 & 7, h = g8 >> 3, hb = h * 8 + b;

    // --- probe permlane32_swap direction (HW variant), wave-uniform ---
    unsigned pva = (unsigned)lane, pvb = 64u + (unsigned)lane;
    asm volatile("v_permlane32_swap_b32 %0, %1" : "+v"(pva), "+v"(pvb));
    const bool v1 = (__builtin_amdgcn_readfirstlane((int)pva) >= 96);

    const ushort_t* QFh = QF + (size_t)(hb * 32 + s) * 2048;
    const ushort_t* KFh = KF + (size_t)hb * 16 * 4096;
    const ushort_t* VFh = VF + (size_t)hb * 16 * 4096;
    const ushort_t* kmr = km16 + (size_t)hb * 1024;

    // Q fragments (B-operand), loop-invariant
    short8 qf[4];
    #pragma unroll
    for (int kc = 0; kc < 4; ++kc)
        qf[kc] = *reinterpret_cast<const short8*>(&QFh[kc * 512 + lane * 8]);

    // per-row shift M: any unpadded key strictly before row q0+l31?
    bool anyPrior = false;
    for (int c = 0; c < (q0 >> 6); ++c) {
        ushort_t v = kmr[c * 64 + lane];
        anyPrior = anyPrior || (__ballot(v != 0) != 0ull);
    }
    float M;
    {
        ushort_t v = kmr[(q0 & ~63) + lane];
        unsigned long long bal = __ballot(v != 0);
        unsigned long long pre = bal & ((1ull << ((q0 & 63) + l31)) - 1ull);
        M = (anyPrior || pre != 0ull) ? 16.f : -9984.f;
    }
    const float cA = -M * LOG2E;
    const float cB = cA - 10000.0f * LOG2E;
    const float S2 = 0.125f * LOG2E;
    const int trow = q0 + l31;

    float lacc = 0.f;
    f32x16 of0, of1;
    #pragma unroll
    for (int i = 0; i < 16; ++i) { of0[i] = 0.f; of1[i] = 0.f; }

    const int ktend = (s == 0) ? 16 : ((s >> 1) + 1);

    for (int kt = 0; kt < ktend; ++kt) {
        const int k0 = kt * 64;
        const ushort_t* KT = &KFh[kt * 4096];
        const ushort_t* VT = &VFh[kt * 4096];

        // K fragments (A-operand): 8 coalesced dwordx4
        short8 kf[2][4];
        #pragma unroll
        for (int f = 0; f < 2; ++f)
            #pragma unroll
            for (int kc = 0; kc < 4; ++kc)
                kf[f][kc] = *reinterpret_cast<const short8*>(&KT[(f * 4 + kc) * 512 + lane * 8]);
        // V fragments c=0,1 issued early
        short8 vfA[2][2];
        #pragma unroll
        for (int c = 0; c < 2; ++c)
            #pragma unroll
            for (int df = 0; df < 2; ++df)
                vfA[c][df] = *reinterpret_cast<const short8*>(&VT[(c * 2 + df) * 512 + lane * 8]);
        // key masks: 4 keys per (f,rr) group
        ushort4 kq[2][4];
        #pragma unroll
        for (int f = 0; f < 2; ++f)
            #pragma unroll
            for (int rr = 0; rr < 4; ++rr)
                kq[f][rr] = *reinterpret_cast<const ushort4*>(&kmr[k0 + f * 32 + rr * 8 + hi * 4]);

        unsigned pk[2][8];
        short8 vfB[2][2];
        #pragma unroll
        for (int f = 0; f < 2; ++f) {
            // S^T = K Q^T over d=64 (4 chained K=16 mfmas)
            f32x16 sf;
            #pragma unroll
            for (int i = 0; i < 16; ++i) sf[i] = 0.f;
            __builtin_amdgcn_s_setprio(1);
            #pragma unroll
            for (int kc = 0; kc < 4; ++kc)
                sf = __builtin_amdgcn_mfma_f32_32x32x16_bf16(kf[f][kc], qf[kc], sf, 0, 0, 0);
            __builtin_amdgcn_s_setprio(0);
            if (f == 0) {   // issue V c=2,3 loads under softmax
                #pragma unroll
                for (int c = 0; c < 2; ++c)
                    #pragma unroll
                    for (int df = 0; df < 2; ++df)
                        vfB[c][df] = *reinterpret_cast<const short8*>(
                            &VT[((c + 2) * 2 + df) * 512 + lane * 8]);
            }
            // fixed-shift softmax in exp2 domain; immediate bf16 pack
            #pragma unroll
            for (int rr = 0; rr < 4; ++rr) {
                const int kbase = k0 + f * 32 + rr * 8 + hi * 4;
                const ushort_t* kmv = reinterpret_cast<const ushort_t*>(&kq[f][rr]);
                float p[4];
                #pragma unroll
                for (int ri = 0; ri < 4; ++ri) {
                    float cc = (kbase + ri >= trow) ? cB : cA;
                    cc = kmv[ri] ? cc : -1e30f;
                    p[ri] = v_exp2(fmaf(sf[rr * 4 + ri], S2, cc));
                    lacc += p[ri];
                }
                pk[f][rr * 2 + 0] = cvt_pk_bf16(p[0], p[1]);
                pk[f][rr * 2 + 1] = cvt_pk_bf16(p[2], p[3]);
            }
        }

        // PV: assemble A-fragments via permlane32_swap, accumulate O
        #pragma unroll
        for (int c = 0; c < 4; ++c) {
            const int f = c >> 1, o = (c & 1) * 4;
            unsigned a0 = pk[f][o + 0], b0 = pk[f][o + 2];
            unsigned a1 = pk[f][o + 1], b1 = pk[f][o + 3];
            if (v1) {
                asm volatile("v_permlane32_swap_b32 %0, %1" : "+v"(b0), "+v"(a0));
                asm volatile("v_permlane32_swap_b32 %0, %1" : "+v"(b1), "+v"(a1));
            } else {
                asm volatile("v_permlane32_swap_b32 %0, %1" : "+v"(a0), "+v"(b0));
                asm volatile("v_permlane32_swap_b32 %0, %1" : "+v"(a1), "+v"(b1));
            }
            u32x4 pau = {a0, a1, b0, b1};
            short8 pa = __builtin_bit_cast(short8, pau);
            short8 v0 = (c < 2) ? vfA[c][0] : vfB[c - 2][0];
            short8 v1f = (c < 2) ? vfA[c][1] : vfB[c - 2][1];
            __builtin_amdgcn_s_setprio(1);
            of0 = __builtin_amdgcn_mfma_f32_32x32x16_bf16(pa, v0, of0, 0, 0, 0);
            of1 = __builtin_amdgcn_mfma_f32_32x32x16_bf16(pa, v1f, of1, 0, 0, 0);
            __builtin_amdgcn_s_setprio(0);
        }
    }

    // epilogue: row scale qs/l distributed via tiny per-wave LDS slice
    float ltot = lacc + __shfl_xor(lacc, 32);
    if (hi == 0)
        scs[wave][l31] = qs[(size_t)hb * 1024 + q0 + l31] / ltot;
    const size_t obase = ((size_t)b * T_DIM + q0) * D_DIM + h * 64;
    #pragma unroll
    for (int reg = 0; reg < 16; ++reg) {
        const int qrow = (reg & 3) + 8 * (reg >> 2) + 4 * hi;
        const float sc = scs[wave][qrow];
        out[obase + (size_t)qrow * D_DIM + l31]      = of0[reg] * sc;
        out[obase + (size_t)qrow * D_DIM + 32 + l31] = of1[reg] * sc;
    }
}

// ---------------------------------------------------------------------------
extern "C" void kernel_launch(void* const* d_in, const int* in_sizes, int n_in,
                              void* d_out, int out_size, void* d_ws, size_t ws_size,
                              hipStream_t stream)
{
    const float* x   = (const float*)d_in[0];
    const int*   msk = (const int*)d_in[1];
    const float* Wq  = (const float*)d_in[2];
    const float* Wk  = (const float*)d_in[3];
    const float* Wv  = (const float*)d_in[4];
    float* out = (float*)d_out;

    // workspace layout (bytes)
    char* ws = (char*)d_ws;
    ushort_t* xb = (ushort_t*)(ws);                    // 10,485,760
    ushort_t* Wt = (ushort_t*)(ws + 10485760);         //  2,457,600
    ushort_t* QF = (ushort_t*)(ws + 12943360);         // 10,485,760
    ushort_t* KF = (ushort_t*)(ws + 23429120);         // 10,485,760
    ushort_t* VF = (ushort_t*)(ws + 33914880);         // 10,485,760
    float*    qs = (float*)(ws + 44400640);            //    327,680
    ushort_t* km = (ushort_t*)(ws + 44728320);         //    163,840
    if (ws_size < 44892160) return;

    convwt<<<2348, 256, 0, stream>>>(x, Wq, Wk, Wv, xb, Wt);
    gemm_qkv<<<960, 256, 0, stream>>>(xb, Wt, msk, QF, KF, VF, qs, km);
    attn_wave<<<640, 256, 0, stream>>>(QF, KF, VF, qs, km, out);
}